// Round 5
// baseline (3211.242 us; speedup 1.0000x reference)
//
#include <hip/hip_runtime.h>
#include <hip/hip_bf16.h>
#include <stdint.h>

#define T_SEQ 2048
#define DDIM 256
#define G3 768
#define NB 64
#define NQR 10

typedef _Float16 h2f __attribute__((ext_vector_type(2)));
typedef unsigned u32x4 __attribute__((ext_vector_type(4)));

__device__ __forceinline__ float fdot2u(unsigned a, unsigned b, float c) {
    return __builtin_amdgcn_fdot2(__builtin_bit_cast(h2f, a),
                                  __builtin_bit_cast(h2f, b), c, false);
}
__device__ __forceinline__ unsigned packf16(float a, float b) {
    auto p = __builtin_amdgcn_cvt_pkrtz(a, b);   // __fp16 ext_vector(2)
    return __builtin_bit_cast(unsigned, p);
}
__device__ __forceinline__ float sigmf(float x) { return 1.0f / (1.0f + __expf(-x)); }
__device__ __forceinline__ float tanhff(float x) {
    float ax = fabsf(x);
    float e = __expf(2.0f * ax);
    float t = 1.0f - 2.0f / (e + 1.0f);
    return copysignf(t, x);
}

// ---------------- prologue: span selection + wcol + bsum ----------------
__global__ __launch_bounds__(256) void k_prologue(
    const float* __restrict__ logits, const float* __restrict__ spans,
    const float* __restrict__ W_sal, const float* __restrict__ b_sal,
    int* __restrict__ meta, float* __restrict__ wcol, float* __restrict__ bsum) {
    int tid = threadIdx.x;
    if (tid < NB) {
        int b = tid;
        float bestv = -1e30f; int best = 0;
        for (int q = 0; q < NQR; ++q) {
            float l0 = logits[(b * NQR + q) * 2 + 0];
            float l1 = logits[(b * NQR + q) * 2 + 1];
            float sc = sigmf(l0 - l1);   // monotone in softmax[...,0]
            if (sc > bestv) { bestv = sc; best = q; }
        }
        float cx = spans[(b * NQR + best) * 2 + 0];
        float w  = spans[(b * NQR + best) * 2 + 1];
        float x0 = (cx - 0.5f * w) * (float)(T_SEQ * 2);
        float x1 = (cx + 0.5f * w) * (float)(T_SEQ * 2);
        int se0 = (int)floorf(x0 * 0.5f);
        int se1 = (int)floorf(x1 * 0.5f);
        int start = min(max(se0, 0), T_SEQ - 1);
        int end_eff = min(se1, T_SEQ - 1);
        int len = end_eff - start + 1;
        if (len < 0) len = 0;
        meta[b] = start; meta[NB + b] = len;
    }
    float acc = 0.f;
    for (int e = 0; e < DDIM; ++e) acc += W_sal[e * DDIM + tid];
    wcol[tid] = acc;
    if (tid < 64) {
        float p = b_sal[tid] + b_sal[tid + 64] + b_sal[tid + 128] + b_sal[tid + 192];
        for (int off = 32; off; off >>= 1) p += __shfl_down(p, off, 64);
        if (tid == 0) *bsum = p;
    }
}

// ---------------- prep: transpose W_ih + pack W_hh to u32x4 f16 quads ----------
// w4 layout (as uint4): w4[kq*768 + u].e = packf16 pair (4*kq+e) of row u,
// i.e. (W_hh[u][8kq+2e], W_hh[u][8kq+2e+1]).  kq in [0,32), u in [0,768).
__global__ __launch_bounds__(256) void k_prep(
    const float* __restrict__ W_ih, const float* __restrict__ W_hh,
    float* __restrict__ wt_ih, unsigned* __restrict__ w4) {
    int g = blockIdx.x, k = threadIdx.x;
    wt_ih[k * G3 + g] = W_ih[g * DDIM + k];
    if (k < 128) {  // k = pair index kk
        unsigned v = packf16(W_hh[g * DDIM + 2 * k], W_hh[g * DDIM + 2 * k + 1]);
        w4[((k >> 2) * G3 + g) * 4 + (k & 3)] = v;
    }
}

// ---------------- gi GEMM: gi[b,t,g] = sliced[b,t,:]@W_ih[g,:] + b_ih ----------------
__global__ __launch_bounds__(256) void k_gemm(
    const float* __restrict__ src_vid, const float* __restrict__ wt_ih,
    const float* __restrict__ b_ih, const int* __restrict__ meta,
    float* __restrict__ gi, int t0, int tc, int TC) {
    int b = blockIdx.y;
    int len = meta[NB + b];
    int tb = t0 + blockIdx.x * 16;
    int tcap = t0 + tc; if (tcap > len) tcap = len;
    if (tb >= tcap) return;
    int start = meta[b];
    int j = threadIdx.x;
    int nval = tcap - tb; if (nval > 16) nval = 16;
    float aR[16], aZ[16], aN[16];
    float bR = b_ih[j], bZ = b_ih[DDIM + j], bN = b_ih[2 * DDIM + j];
#pragma unroll
    for (int r = 0; r < 16; ++r) { aR[r] = bR; aZ[r] = bZ; aN[r] = bN; }
    const float* xb = src_vid + ((size_t)b * T_SEQ + start + tb) * DDIM;
    for (int kq = 0; kq < 64; ++kq) {
        float4 xq[16];
#pragma unroll
        for (int r = 0; r < 16; ++r) {
            if (r < nval) xq[r] = *(const float4*)(xb + r * DDIM + kq * 4);
            else          xq[r] = make_float4(0.f, 0.f, 0.f, 0.f);
        }
#pragma unroll
        for (int e = 0; e < 4; ++e) {
            int k = kq * 4 + e;
            float wR = wt_ih[k * G3 + j];
            float wZ = wt_ih[k * G3 + DDIM + j];
            float wN = wt_ih[k * G3 + 2 * DDIM + j];
#pragma unroll
            for (int r = 0; r < 16; ++r) {
                float xv = (e == 0) ? xq[r].x : (e == 1) ? xq[r].y : (e == 2) ? xq[r].z : xq[r].w;
                aR[r] = fmaf(xv, wR, aR[r]);
                aZ[r] = fmaf(xv, wZ, aZ[r]);
                aN[r] = fmaf(xv, wN, aN[r]);
            }
        }
    }
    float* go = gi + ((size_t)b * TC + (tb - t0)) * G3;
    for (int r = 0; r < nval; ++r) {
        go[r * G3 + j] = aR[r];
        go[r * G3 + DDIM + j] = aZ[r];
        go[r * G3 + 2 * DDIM + j] = aN[r];
    }
}

// ---------------- GRU recurrence (v_dot2, full-dot-per-thread) ----------------
// 768 threads/block (12 waves, 3/SIMD), one block per batch.
// Thread u = gate*256 + col owns the FULL 256-k dot product of W_hh row u:
// 32 u32x4 packed-f16 weight quads resident in VGPRs (~155 total < 170 =
// 512/3 per-SIMD budget at 3 waves/SIMD -> no spill, no AGPR).
// Gate split: g0 -> r (sigm before barrier), g1 -> z, g2 -> owns h, computes
// n = tanh(gN + r*hn) and the update after the barrier.
__global__ void __launch_bounds__(768, 3) k_gru(
    const float* __restrict__ gi, const unsigned* __restrict__ w4,
    const float* __restrict__ b_ih, const float* __restrict__ b_hh,
    const int* __restrict__ meta, float* __restrict__ h_state,
    int t0, int t1, int TC) {
    int b = blockIdx.x, u = threadIdx.x;
    int c = u & 255;
    int len = meta[NB + b];

    // resident weights: 32 x uint4, coalesced 16B/lane
    u32x4 wq[32];
    const u32x4* w4v = (const u32x4*)w4;
#pragma unroll
    for (int kq = 0; kq < 32; ++kq) wq[kq] = w4v[kq * G3 + u];

    float bh = b_hh[u];
    float bi = b_ih[u];

    __shared__ unsigned hl[128];   // packed f16 h (256 values)
    __shared__ float rl[256];      // r gate
    __shared__ float zl[256];      // z gate

    float h = 0.f;
    if (u >= 512) {                // g2 owns h
        if (t0 != 0) h = h_state[b * DDIM + c];
        float hp = __shfl_xor(h, 1, 64);
        if (!(c & 1)) hl[c >> 1] = packf16(h, hp);
    }

    const float* gbase = gi + (size_t)b * TC * G3;
    float gv = bi;
    if (t0 < t1 && t0 < len) gv = gbase[u];
    __syncthreads();

    for (int t = t0; t < t1; ++t) {
        // prefetch next-step gi (hides under the dot chain)
        float nv = bi;
        int tn = t + 1;
        if (tn < t1 && tn < len) nv = gbase[(size_t)(tn - t0) * G3 + u];
        // 128 fdot2 over packed h (uniform/broadcast LDS reads)
        float a0 = 0.f, a1 = 0.f, a2 = 0.f, a3 = 0.f;
        const u32x4* hb = (const u32x4*)hl;
#pragma unroll
        for (int kq = 0; kq < 32; ++kq) {
            u32x4 h4 = hb[kq];
            a0 = fdot2u(h4.x, wq[kq].x, a0);
            a1 = fdot2u(h4.y, wq[kq].y, a1);
            a2 = fdot2u(h4.z, wq[kq].z, a2);
            a3 = fdot2u(h4.w, wq[kq].w, a3);
        }
        float dot = (a0 + a1) + (a2 + a3);
        if (u < 256)      rl[c] = sigmf(gv + dot + bh);
        else if (u < 512) zl[c] = sigmf(gv + dot + bh);
        __syncthreads();
        if (u >= 512) {
            float r = rl[c], z = zl[c];
            float n = tanhff(gv + r * (dot + bh));
            h = (1.0f - z) * n + z * h;
            float hp = __shfl_xor(h, 1, 64);
            if (!(c & 1)) hl[c >> 1] = packf16(h, hp);
        }
        gv = nv;
        __syncthreads();
    }
    if (u >= 512) h_state[b * DDIM + c] = h;
}

// ---------------- epilogue: saliency = ((1+h·src)·(mem·wcol)+bsum)/16 ----------------
__global__ __launch_bounds__(256) void k_epi(
    const float* __restrict__ memory, const float* __restrict__ src_vid,
    const float* __restrict__ h_state, const float* __restrict__ wcol,
    const float* __restrict__ bsum, float* __restrict__ out) {
    int wid = blockIdx.x * 4 + (threadIdx.x >> 6);
    int lane = threadIdx.x & 63;
    int b = wid >> 11;
    int t = wid & 2047;
    const float4* mp = (const float4*)(memory + ((size_t)b * T_SEQ + t) * DDIM);
    const float4* sp = (const float4*)(src_vid + ((size_t)b * T_SEQ + t) * DDIM);
    const float4* hp = (const float4*)(h_state + b * DDIM);
    const float4* wp = (const float4*)wcol;
    float4 m = mp[lane], s = sp[lane], hv = hp[lane], wc = wp[lane];
    float s1 = m.x * wc.x + m.y * wc.y + m.z * wc.z + m.w * wc.w;
    float s2 = hv.x * s.x + hv.y * s.y + hv.z * s.z + hv.w * s.w;
    for (int off = 32; off; off >>= 1) {
        s1 += __shfl_down(s1, off, 64);
        s2 += __shfl_down(s2, off, 64);
    }
    if (lane == 0) out[(size_t)b * T_SEQ + t] = ((1.0f + s2) * s1 + *bsum) * 0.0625f;
}

extern "C" void kernel_launch(void* const* d_in, const int* in_sizes, int n_in,
                              void* d_out, int out_size, void* d_ws, size_t ws_size,
                              hipStream_t stream) {
    const float* logits  = (const float*)d_in[0];
    const float* spans   = (const float*)d_in[1];
    const float* memory  = (const float*)d_in[2];
    const float* src_vid = (const float*)d_in[3];
    const float* W_ih    = (const float*)d_in[4];
    const float* W_hh    = (const float*)d_in[5];
    const float* b_ih    = (const float*)d_in[6];
    const float* b_hh    = (const float*)d_in[7];
    const float* W_sal   = (const float*)d_in[8];
    const float* b_sal   = (const float*)d_in[9];
    float* out = (float*)d_out;
    char* ws = (char*)d_ws;

    const size_t OFF_META = 0;        // 128 ints
    const size_t OFF_WCOL = 1024;     // 256 f32
    const size_t OFF_BSUM = 2048;     // 1 f32
    const size_t OFF_H    = 4096;     // 64*256 f32 = 65536
    const size_t OFF_W4   = 69632;    // 98304 u32 = 393216
    const size_t OFF_WTIH = 462848;   // 256*768 f32 = 786432
    const size_t OFF_GI   = 1249280;  // up to 64*2048*768 f32

    int* meta       = (int*)(ws + OFF_META);
    float* wcol     = (float*)(ws + OFF_WCOL);
    float* bsum     = (float*)(ws + OFF_BSUM);
    float* h_state  = (float*)(ws + OFF_H);
    unsigned* w4    = (unsigned*)(ws + OFF_W4);
    float* wt_ih    = (float*)(ws + OFF_WTIH);
    float* gi       = (float*)(ws + OFF_GI);

    size_t gi_cap = (ws_size > OFF_GI) ? (ws_size - OFF_GI) : 0;
    long long tc_max = (long long)(gi_cap / ((size_t)NB * G3 * 4));
    int TC = (tc_max > T_SEQ) ? T_SEQ : (int)tc_max;
    if (TC < 1) TC = 1;

    k_prologue<<<dim3(1), dim3(256), 0, stream>>>(logits, spans, W_sal, b_sal, meta, wcol, bsum);
    k_prep<<<dim3(G3), dim3(256), 0, stream>>>(W_ih, W_hh, wt_ih, w4);
    for (int t0 = 0; t0 < T_SEQ; t0 += TC) {
        int tc = T_SEQ - t0; if (tc > TC) tc = TC;
        k_gemm<<<dim3((tc + 15) / 16, NB), dim3(256), 0, stream>>>(
            src_vid, wt_ih, b_ih, meta, gi, t0, tc, TC);
        k_gru<<<dim3(NB), dim3(768), 0, stream>>>(
            gi, w4, b_ih, b_hh, meta, h_state, t0, t0 + tc, TC);
    }
    k_epi<<<dim3(NB * T_SEQ / 4), dim3(256), 0, stream>>>(
        memory, src_vid, h_state, wcol, bsum, out);
}

// Round 6
// 2993.245 us; speedup vs baseline: 1.0728x; 1.0728x over previous
//
#include <hip/hip_runtime.h>
#include <hip/hip_bf16.h>
#include <stdint.h>

#define T_SEQ 2048
#define DDIM 256
#define G3 768
#define NB 64
#define NQR 10

typedef _Float16 h2f __attribute__((ext_vector_type(2)));
typedef unsigned u32x4 __attribute__((ext_vector_type(4)));

__device__ __forceinline__ float fdot2u(unsigned a, unsigned b, float c) {
    return __builtin_amdgcn_fdot2(__builtin_bit_cast(h2f, a),
                                  __builtin_bit_cast(h2f, b), c, false);
}
__device__ __forceinline__ unsigned packf16(float a, float b) {
    auto p = __builtin_amdgcn_cvt_pkrtz(a, b);   // __fp16 ext_vector(2)
    return __builtin_bit_cast(unsigned, p);
}
__device__ __forceinline__ float unpk(unsigned u, int hi) {
    unsigned w = hi ? (u >> 16) : u;
    h2f p = __builtin_bit_cast(h2f, w);
    return (float)p[0];
}
__device__ __forceinline__ float sigmf(float x) { return 1.0f / (1.0f + __expf(-x)); }
__device__ __forceinline__ float tanhff(float x) {
    float ax = fabsf(x);
    float e = __expf(2.0f * ax);
    float t = 1.0f - 2.0f / (e + 1.0f);
    return copysignf(t, x);
}

// force a 128-bit value to live in arch VGPRs at this program point
#define PIN4(x) asm volatile("" : "+v"(x))

// ---------------- prologue: span selection + wcol + bsum ----------------
__global__ __launch_bounds__(256) void k_prologue(
    const float* __restrict__ logits, const float* __restrict__ spans,
    const float* __restrict__ W_sal, const float* __restrict__ b_sal,
    int* __restrict__ meta, float* __restrict__ wcol, float* __restrict__ bsum) {
    int tid = threadIdx.x;
    if (tid < NB) {
        int b = tid;
        float bestv = -1e30f; int best = 0;
        for (int q = 0; q < NQR; ++q) {
            float l0 = logits[(b * NQR + q) * 2 + 0];
            float l1 = logits[(b * NQR + q) * 2 + 1];
            float sc = sigmf(l0 - l1);   // monotone in softmax[...,0]
            if (sc > bestv) { bestv = sc; best = q; }
        }
        float cx = spans[(b * NQR + best) * 2 + 0];
        float w  = spans[(b * NQR + best) * 2 + 1];
        float x0 = (cx - 0.5f * w) * (float)(T_SEQ * 2);
        float x1 = (cx + 0.5f * w) * (float)(T_SEQ * 2);
        int se0 = (int)floorf(x0 * 0.5f);
        int se1 = (int)floorf(x1 * 0.5f);
        int start = min(max(se0, 0), T_SEQ - 1);
        int end_eff = min(se1, T_SEQ - 1);
        int len = end_eff - start + 1;
        if (len < 0) len = 0;
        meta[b] = start; meta[NB + b] = len;
    }
    float acc = 0.f;
    for (int e = 0; e < DDIM; ++e) acc += W_sal[e * DDIM + tid];
    wcol[tid] = acc;
    if (tid < 64) {
        float p = b_sal[tid] + b_sal[tid + 64] + b_sal[tid + 128] + b_sal[tid + 192];
        for (int off = 32; off; off >>= 1) p += __shfl_down(p, off, 64);
        if (tid == 0) *bsum = p;
    }
}

// ---------------- prep: transpose W_ih + pack W_hh to u32x4 f16 quads ----------
// w4 quad (kq, u): pairs 4kq..4kq+3 of row u, i.e. k in [8kq, 8kq+8).
__global__ __launch_bounds__(256) void k_prep(
    const float* __restrict__ W_ih, const float* __restrict__ W_hh,
    float* __restrict__ wt_ih, unsigned* __restrict__ w4) {
    int g = blockIdx.x, k = threadIdx.x;
    wt_ih[k * G3 + g] = W_ih[g * DDIM + k];
    if (k < 128) {  // k = pair index
        unsigned v = packf16(W_hh[g * DDIM + 2 * k], W_hh[g * DDIM + 2 * k + 1]);
        w4[((k >> 2) * G3 + g) * 4 + (k & 3)] = v;
    }
}

// ---------------- gi GEMM: gi[b,t,g] = sliced[b,t,:]@W_ih[g,:] + b_ih ----------------
// output packed f16 pairs: gi2[(b*TC+t)*384 + gate*128 + (col>>1)]
__global__ __launch_bounds__(256) void k_gemm(
    const float* __restrict__ src_vid, const float* __restrict__ wt_ih,
    const float* __restrict__ b_ih, const int* __restrict__ meta,
    unsigned* __restrict__ gi2, int t0, int tc, int TC) {
    int b = blockIdx.y;
    int len = meta[NB + b];
    int tb = t0 + blockIdx.x * 16;
    int tcap = t0 + tc; if (tcap > len) tcap = len;
    if (tb >= tcap) return;
    int start = meta[b];
    int j = threadIdx.x;
    int nval = tcap - tb; if (nval > 16) nval = 16;
    float aR[16], aZ[16], aN[16];
    float bR = b_ih[j], bZ = b_ih[DDIM + j], bN = b_ih[2 * DDIM + j];
#pragma unroll
    for (int r = 0; r < 16; ++r) { aR[r] = bR; aZ[r] = bZ; aN[r] = bN; }
    const float* xb = src_vid + ((size_t)b * T_SEQ + start + tb) * DDIM;
    for (int kq = 0; kq < 64; ++kq) {
        float4 xq[16];
#pragma unroll
        for (int r = 0; r < 16; ++r) {
            if (r < nval) xq[r] = *(const float4*)(xb + r * DDIM + kq * 4);
            else          xq[r] = make_float4(0.f, 0.f, 0.f, 0.f);
        }
#pragma unroll
        for (int e = 0; e < 4; ++e) {
            int k = kq * 4 + e;
            float wR = wt_ih[k * G3 + j];
            float wZ = wt_ih[k * G3 + DDIM + j];
            float wN = wt_ih[k * G3 + 2 * DDIM + j];
#pragma unroll
            for (int r = 0; r < 16; ++r) {
                float xv = (e == 0) ? xq[r].x : (e == 1) ? xq[r].y : (e == 2) ? xq[r].z : xq[r].w;
                aR[r] = fmaf(xv, wR, aR[r]);
                aZ[r] = fmaf(xv, wZ, aZ[r]);
                aN[r] = fmaf(xv, wN, aN[r]);
            }
        }
    }
    unsigned* go = gi2 + ((size_t)b * TC + (tb - t0)) * 384;
    for (int r = 0; r < nval; ++r) {
        float oR = __shfl_xor(aR[r], 1, 64);
        float oZ = __shfl_xor(aZ[r], 1, 64);
        float oN = __shfl_xor(aN[r], 1, 64);
        if (!(j & 1)) {
            unsigned* gw = go + (size_t)r * 384 + (j >> 1);
            gw[0]   = packf16(aR[r], oR);
            gw[128] = packf16(aZ[r], oZ);
            gw[256] = packf16(aN[r], oN);
        }
    }
}

// ---------------- GRU recurrence (v_dot2, weights pinned in arch VGPRs) --------
// 512 threads/block (8 waves, 2/SIMD), one block per batch.
// Thread (c, half): owns 3 gates of col c over K-half [half*128, half*128+128):
// 48 u32x4 packed-f16 weight quads (192 regs) FORCED into arch VGPRs by PIN4.
__global__ void __launch_bounds__(512)
__attribute__((amdgpu_waves_per_eu(2, 2))) k_gru(
    const unsigned* __restrict__ gi2, const unsigned* __restrict__ w4,
    const float* __restrict__ b_ih, const float* __restrict__ b_hh,
    const int* __restrict__ meta, float* __restrict__ h_state,
    int t0, int t1, int TC) {
    int b = blockIdx.x, tid = threadIdx.x;
    int c = tid & 255, half = tid >> 8;
    int len = meta[NB + b];

    // resident weights: 48 quads, coalesced 16B/lane loads
    u32x4 wrq[16], wzq[16], wnq[16];
    const u32x4* w4v = (const u32x4*)w4;
    const u32x4* wb = w4v + (size_t)(half * 16) * G3;
#pragma unroll
    for (int q = 0; q < 16; ++q) {
        wrq[q] = wb[q * G3 + c];
        wzq[q] = wb[q * G3 + 256 + c];
        wnq[q] = wb[q * G3 + 512 + c];
    }
#pragma unroll
    for (int q = 0; q < 16; ++q) { PIN4(wrq[q]); PIN4(wzq[q]); PIN4(wnq[q]); }

    float bhR = (half == 0) ? b_hh[c] : 0.f;
    float bhZ = (half == 0) ? b_hh[256 + c] : 0.f;
    float bhN = (half == 0) ? b_hh[512 + c] : 0.f;
    float biR = b_ih[c], biZ = b_ih[256 + c], biN = b_ih[512 + c];

    __shared__ unsigned hl[128];   // packed f16 h (256 values)
    __shared__ float pl[3][256];   // half1 partial sums

    float h = 0.f;
    if (half == 0) {
        if (t0 != 0) h = h_state[b * DDIM + c];
        float hp = __shfl_xor(h, 1, 64);
        if (!(c & 1)) hl[c >> 1] = packf16(h, hp);
    }

    const unsigned* gb2 = gi2 + (size_t)b * TC * 384 + (c >> 1);
    int sel = c & 1;
    float gR = biR, gZ = biZ, gN = biN;
    if (half == 0 && t0 < t1 && t0 < len) {
        gR = unpk(gb2[0], sel); gZ = unpk(gb2[128], sel); gN = unpk(gb2[256], sel);
    }
    __syncthreads();

    for (int t = t0; t < t1; ++t) {
        // prefetch next-step gi (hides under the dot chain)
        float nR = biR, nZ = biZ, nN = biN;
        int tn = t + 1;
        if (half == 0 && tn < t1 && tn < len) {
            const unsigned* gp = gb2 + (size_t)(tn - t0) * 384;
            nR = unpk(gp[0], sel); nZ = unpk(gp[128], sel); nN = unpk(gp[256], sel);
        }
        // pin weights in arch VGPRs for this iteration
#pragma unroll
        for (int q = 0; q < 16; ++q) { PIN4(wrq[q]); PIN4(wzq[q]); PIN4(wnq[q]); }
        // 192 fdot2 over own K-half (uniform/broadcast LDS reads)
        float r0 = bhR, z0 = bhZ, n0 = bhN, r1 = 0.f, z1 = 0.f, n1 = 0.f;
        const u32x4* hb = (const u32x4*)hl + half * 16;
#pragma unroll
        for (int q = 0; q < 16; ++q) {
            u32x4 h4 = hb[q];
            r0 = fdot2u(h4.x, wrq[q].x, r0);
            z0 = fdot2u(h4.x, wzq[q].x, z0);
            n0 = fdot2u(h4.x, wnq[q].x, n0);
            r1 = fdot2u(h4.y, wrq[q].y, r1);
            z1 = fdot2u(h4.y, wzq[q].y, z1);
            n1 = fdot2u(h4.y, wnq[q].y, n1);
            r0 = fdot2u(h4.z, wrq[q].z, r0);
            z0 = fdot2u(h4.z, wzq[q].z, z0);
            n0 = fdot2u(h4.z, wnq[q].z, n0);
            r1 = fdot2u(h4.w, wrq[q].w, r1);
            z1 = fdot2u(h4.w, wzq[q].w, z1);
            n1 = fdot2u(h4.w, wnq[q].w, n1);
        }
        float hr = r0 + r1, hz = z0 + z1, hn = n0 + n1;
        if (half == 1) {
            pl[0][c] = hr; pl[1][c] = hz; pl[2][c] = hn;
        }
        __syncthreads();
        if (half == 0) {
            hr += pl[0][c]; hz += pl[1][c]; hn += pl[2][c];
            float r = sigmf(gR + hr);
            float z = sigmf(gZ + hz);
            float n = tanhff(gN + r * hn);
            h = (1.0f - z) * n + z * h;
            float hp = __shfl_xor(h, 1, 64);
            if (!(c & 1)) hl[c >> 1] = packf16(h, hp);
        }
        gR = nR; gZ = nZ; gN = nN;
        __syncthreads();
    }
    if (half == 0) h_state[b * DDIM + c] = h;
}

// ---------------- epilogue: saliency = ((1+h·src)·(mem·wcol)+bsum)/16 ----------------
__global__ __launch_bounds__(256) void k_epi(
    const float* __restrict__ memory, const float* __restrict__ src_vid,
    const float* __restrict__ h_state, const float* __restrict__ wcol,
    const float* __restrict__ bsum, float* __restrict__ out) {
    int wid = blockIdx.x * 4 + (threadIdx.x >> 6);
    int lane = threadIdx.x & 63;
    int b = wid >> 11;
    int t = wid & 2047;
    const float4* mp = (const float4*)(memory + ((size_t)b * T_SEQ + t) * DDIM);
    const float4* sp = (const float4*)(src_vid + ((size_t)b * T_SEQ + t) * DDIM);
    const float4* hp = (const float4*)(h_state + b * DDIM);
    const float4* wp = (const float4*)wcol;
    float4 m = mp[lane], s = sp[lane], hv = hp[lane], wc = wp[lane];
    float s1 = m.x * wc.x + m.y * wc.y + m.z * wc.z + m.w * wc.w;
    float s2 = hv.x * s.x + hv.y * s.y + hv.z * s.z + hv.w * s.w;
    for (int off = 32; off; off >>= 1) {
        s1 += __shfl_down(s1, off, 64);
        s2 += __shfl_down(s2, off, 64);
    }
    if (lane == 0) out[(size_t)b * T_SEQ + t] = ((1.0f + s2) * s1 + *bsum) * 0.0625f;
}

extern "C" void kernel_launch(void* const* d_in, const int* in_sizes, int n_in,
                              void* d_out, int out_size, void* d_ws, size_t ws_size,
                              hipStream_t stream) {
    const float* logits  = (const float*)d_in[0];
    const float* spans   = (const float*)d_in[1];
    const float* memory  = (const float*)d_in[2];
    const float* src_vid = (const float*)d_in[3];
    const float* W_ih    = (const float*)d_in[4];
    const float* W_hh    = (const float*)d_in[5];
    const float* b_ih    = (const float*)d_in[6];
    const float* b_hh    = (const float*)d_in[7];
    const float* W_sal   = (const float*)d_in[8];
    const float* b_sal   = (const float*)d_in[9];
    float* out = (float*)d_out;
    char* ws = (char*)d_ws;

    const size_t OFF_META = 0;        // 128 ints
    const size_t OFF_WCOL = 1024;     // 256 f32
    const size_t OFF_BSUM = 2048;     // 1 f32
    const size_t OFF_H    = 4096;     // 64*256 f32 = 65536
    const size_t OFF_W4   = 69632;    // 98304 u32 = 393216
    const size_t OFF_WTIH = 462848;   // 256*768 f32 = 786432
    const size_t OFF_GI   = 1249280;  // gi2 packed f16 pairs

    int* meta       = (int*)(ws + OFF_META);
    float* wcol     = (float*)(ws + OFF_WCOL);
    float* bsum     = (float*)(ws + OFF_BSUM);
    float* h_state  = (float*)(ws + OFF_H);
    unsigned* w4    = (unsigned*)(ws + OFF_W4);
    float* wt_ih    = (float*)(ws + OFF_WTIH);
    unsigned* gi2   = (unsigned*)(ws + OFF_GI);

    size_t gi_cap = (ws_size > OFF_GI) ? (ws_size - OFF_GI) : 0;
    long long tc_max = (long long)(gi_cap / ((size_t)NB * 384 * 4));
    int TC = (tc_max > T_SEQ) ? T_SEQ : (int)tc_max;
    if (TC < 16) TC = 16;

    k_prologue<<<dim3(1), dim3(256), 0, stream>>>(logits, spans, W_sal, b_sal, meta, wcol, bsum);
    k_prep<<<dim3(G3), dim3(256), 0, stream>>>(W_ih, W_hh, wt_ih, w4);
    for (int t0 = 0; t0 < T_SEQ; t0 += TC) {
        int tc = T_SEQ - t0; if (tc > TC) tc = TC;
        k_gemm<<<dim3((tc + 15) / 16, NB), dim3(256), 0, stream>>>(
            src_vid, wt_ih, b_ih, meta, gi2, t0, tc, TC);
        k_gru<<<dim3(NB), dim3(512), 0, stream>>>(
            gi2, w4, b_ih, b_hh, meta, h_state, t0, t0 + tc, TC);
    }
    k_epi<<<dim3(NB * T_SEQ / 4), dim3(256), 0, stream>>>(
        memory, src_vid, h_state, wcol, bsum, out);
}